// Round 2
// baseline (1590.957 us; speedup 1.0000x reference)
//
#include <hip/hip_runtime.h>

namespace {

constexpr int NFFT  = 65536;   // complex FFT length (half of 131072)
constexpr int OUTW  = 65409;   // W - K + 1
// Y2[k1][m][f][c] : weight rfft spectrum, column-major for the fused MAC
constexpr size_t Y2BYTES = (size_t)256 * 129 * 128 * 8;

typedef float2 cplx;

__device__ __forceinline__ cplx cmk(float x, float y){ return make_float2(x, y); }
__device__ __forceinline__ cplx cadd(cplx a, cplx b){ return cmk(a.x+b.x, a.y+b.y); }
__device__ __forceinline__ cplx csub(cplx a, cplx b){ return cmk(a.x-b.x, a.y-b.y); }
__device__ __forceinline__ cplx cmul(cplx a, cplx b){ return cmk(a.x*b.x - a.y*b.y, a.x*b.y + a.y*b.x); }
__device__ __forceinline__ cplx cmulj(cplx a, cplx b){ // a * conj(b)
  return cmk(a.x*b.x + a.y*b.y, a.y*b.x - a.x*b.y); }

// 16-point complex DFT, natural order in/out. DIR=-1 forward (e^{-i}), +1 inverse (unnormalized).
template<int DIR>
__device__ __forceinline__ void dft16(cplx v[16]) {
  const float C1 = 0.92387953251128674f;
  const float S1 = 0.38268343236508977f;
  const float C2 = 0.70710678118654752f;
  const float WR[16]  = {1.f, C1, C2, S1, 0.f, -S1, -C2, -C1, -1.f, -C1, -C2, -S1, 0.f, S1, C2, C1};
  const float WIF[16] = {0.f, -S1, -C2, -C1, -1.f, -C1, -C2, -S1, 0.f, S1, C2, C1, 1.f, C1, C2, S1};
  cplx s[16];
  #pragma unroll
  for (int n2 = 0; n2 < 4; ++n2) {
    cplx a = v[n2], b = v[n2+4], c = v[n2+8], d = v[n2+12];
    cplx ac = cadd(a,c), am = csub(a,c), bd = cadd(b,d), bm = csub(b,d);
    cplx x0 = cadd(ac, bd), x2 = csub(ac, bd), x1, x3;
    if (DIR == -1) { x1 = cmk(am.x + bm.y, am.y - bm.x); x3 = cmk(am.x - bm.y, am.y + bm.x); }
    else           { x1 = cmk(am.x - bm.y, am.y + bm.x); x3 = cmk(am.x + bm.y, am.y - bm.x); }
    s[0*4+n2] = x0;
    {
      int e1 = (n2*1) & 15, e2 = (n2*2) & 15, e3 = (n2*3) & 15;
      cplx w1 = cmk(WR[e1], (DIR==-1)? WIF[e1] : -WIF[e1]);
      cplx w2 = cmk(WR[e2], (DIR==-1)? WIF[e2] : -WIF[e2]);
      cplx w3 = cmk(WR[e3], (DIR==-1)? WIF[e3] : -WIF[e3]);
      s[1*4+n2] = cmul(x1, w1);
      s[2*4+n2] = cmul(x2, w2);
      s[3*4+n2] = cmul(x3, w3);
    }
  }
  #pragma unroll
  for (int t1 = 0; t1 < 4; ++t1) {
    cplx a = s[t1*4+0], b = s[t1*4+1], c = s[t1*4+2], d = s[t1*4+3];
    cplx ac = cadd(a,c), am = csub(a,c), bd = cadd(b,d), bm = csub(b,d);
    cplx x0 = cadd(ac,bd), x2 = csub(ac,bd), x1, x3;
    if (DIR == -1) { x1 = cmk(am.x + bm.y, am.y - bm.x); x3 = cmk(am.x - bm.y, am.y + bm.x); }
    else           { x1 = cmk(am.x - bm.y, am.y + bm.x); x3 = cmk(am.x + bm.y, am.y - bm.x); }
    v[t1+0] = x0; v[t1+4] = x1; v[t1+8] = x2; v[t1+12] = x3;
  }
}

// Four-step pass A (forward): inner 256-pt DFTs + big twiddle.
// Output is k1-major (T[seq][k1*256 + b]) staged through a padded LDS tile so
// global stores are 16-lane-contiguous 128-B segments (round-1 version did
// 64x scattered 8-B stores per wave).
template<int DIR>
__global__ __launch_bounds__(256)
void fft_pass_a(const cplx* __restrict__ in, long inStride, int inLen,
                cplx* __restrict__ T) {
  int blk = blockIdx.x;
  int seq = blk >> 4;
  int B0  = (blk & 15) << 4;
  int t = threadIdx.x;
  __shared__ cplx sm[4608];                    // 36864 B: union of two views
  cplx (*tile)[260] = (cplx(*)[260])sm;        // phase-1 view [16][260]
  cplx* tile2 = sm;                            // phase-2 view [256][18]
  {
    const cplx* src = in + (long)seq * inStride;
    int cb = t & 15, rg = t >> 4;
    #pragma unroll
    for (int i = 0; i < 16; ++i) {
      int a = i*16 + rg;
      int sIdx = a*256 + B0 + cb;
      cplx v = (sIdx < inLen) ? src[sIdx] : cmk(0.f, 0.f);
      tile[cb][a] = v;
    }
  }
  __syncthreads();
  int cc = t >> 4, j = t & 15;
  cplx x[16];
  #pragma unroll
  for (int a1 = 0; a1 < 16; ++a1) x[a1] = tile[cc][a1*16 + j];
  dft16<DIR>(x);
  {
    float sn, cs;
    __sincosf((float)DIR * 6.28318530717958648f * (float)j * (1.0f/256.0f), &sn, &cs);
    cplx r = cmk(cs, sn), cur = r;
    #pragma unroll
    for (int t1 = 1; t1 < 16; ++t1) { x[t1] = cmul(x[t1], cur); cur = cmul(cur, r); }
  }
  __syncthreads();
  #pragma unroll
  for (int t1 = 0; t1 < 16; ++t1) tile[cc][t1*16 + ((j + t1) & 15)] = x[t1];
  __syncthreads();
  #pragma unroll
  for (int a2 = 0; a2 < 16; ++a2) x[a2] = tile[cc][j*16 + ((a2 + j) & 15)];
  dft16<DIR>(x);
  int b = B0 + cc;
  __syncthreads();   // tile reads done; reuse as tile2
  {
    // big twiddle then stage: thread (cc,j) holds x[t2] for b, k1 = j+16*t2
    float sn, cs;
    __sincosf((float)DIR * 6.28318530717958648f * (float)(b*j) * (1.0f/65536.0f), &sn, &cs);
    cplx cur = cmk(cs, sn);
    __sincosf((float)DIR * 6.28318530717958648f * (float)b * (1.0f/4096.0f), &sn, &cs);
    cplx stp = cmk(cs, sn);
    #pragma unroll
    for (int t2 = 0; t2 < 16; ++t2) {
      tile2[(j + 16*t2)*18 + cc] = cmul(x[t2], cur);
      cur = cmul(cur, stp);
    }
  }
  __syncthreads();
  {
    int rg = t >> 4, cb = t & 15;
    cplx* dst = T + (long)seq * NFFT + B0 + cb;
    #pragma unroll
    for (int i = 0; i < 16; ++i) {
      int k1 = i*16 + rg;
      dst[(long)k1 * 256] = tile2[k1*18 + cb];
    }
  }
}

// Four-step pass B (unchanged): outer 256-pt DFTs. MODE 1 = inverse-final
// with bias + truncation at OUTW.
template<int DIR, int MODE>
__global__ __launch_bounds__(256)
void fft_pass_b(const cplx* __restrict__ T, cplx* __restrict__ outZ,
                float* __restrict__ outR, const float* __restrict__ bias,
                int seqBase) {
  int blk = blockIdx.x;
  int seq = blk >> 4;
  int K0  = (blk & 15) << 4;
  int t = threadIdx.x;
  __shared__ cplx tile[16][260];
  {
    const cplx* src = T + (long)seq * NFFT;
    int ck = t & 15, rg = t >> 4;
    #pragma unroll
    for (int i = 0; i < 16; ++i) {
      int b = i*16 + rg;
      tile[ck][b] = src[b*256 + K0 + ck];
    }
  }
  __syncthreads();
  int cc = t >> 4, j = t & 15;
  cplx x[16];
  #pragma unroll
  for (int a1 = 0; a1 < 16; ++a1) x[a1] = tile[cc][a1*16 + j];
  dft16<DIR>(x);
  {
    float sn, cs;
    __sincosf((float)DIR * 6.28318530717958648f * (float)j * (1.0f/256.0f), &sn, &cs);
    cplx r = cmk(cs, sn), cur = r;
    #pragma unroll
    for (int t1 = 1; t1 < 16; ++t1) { x[t1] = cmul(x[t1], cur); cur = cmul(cur, r); }
  }
  __syncthreads();
  #pragma unroll
  for (int t1 = 0; t1 < 16; ++t1) tile[cc][t1*16 + ((j + t1) & 15)] = x[t1];
  __syncthreads();
  #pragma unroll
  for (int a2 = 0; a2 < 16; ++a2) x[a2] = tile[cc][j*16 + ((a2 + j) & 15)];
  dft16<DIR>(x);
  __syncthreads();
  #pragma unroll
  for (int t2 = 0; t2 < 16; ++t2) tile[cc][j + 16*t2] = x[t2];
  __syncthreads();
  int ck2 = t & 15, rg2 = t >> 4;
  if (MODE == 0) {
    cplx* dst = outZ + (long)seq * NFFT + K0 + ck2;
    #pragma unroll
    for (int i = 0; i < 16; ++i) {
      int k2 = i*16 + rg2;
      dst[256*k2] = tile[ck2][k2];
    }
  } else {
    const float sc = 1.0f / 65536.0f;
    int gseq = seqBase + seq;
    float bf = bias[gseq & 15];
    float* dst = outR + (long)gseq * OUTW;
    #pragma unroll
    for (int i = 0; i < 16; ++i) {
      int k2 = i*16 + rg2;
      int s  = K0 + ck2 + 256*k2;
      int tp = 2*s;
      cplx v = tile[ck2][k2];
      if (tp < OUTW)     dst[tp]   = v.x * sc + bf;
      if (tp + 1 < OUTW) dst[tp+1] = v.y * sc + bf;
    }
  }
}

// Direct weight rfft into transposed layout Y2[k1][m][f][c], k = k1 + 256*m.
__global__ __launch_bounds__(256)
void weight_spec(const float* __restrict__ wgt, cplx* __restrict__ Y2) {
  const int k1 = blockIdx.x;      // 0..255
  const int fg = blockIdx.y;      // 0..7  -> fc rows fg*16 .. fg*16+15
  const int t  = threadIdx.x;
  __shared__ float wt[16][129];
  for (int e = t; e < 16*128; e += 256)
    wt[e >> 7][e & 127] = wgt[(fg*16 + (e >> 7))*128 + (e & 127)];
  __syncthreads();
  const int fcL = t & 15;
  const int fc  = fg*16 + fcL;
  for (int m = t >> 4; m < 129; m += 16) {
    int k = k1 + 256*m;
    if (k > 32768) break;
    float sn, cs;
    __sincosf(-3.14159265358979324f * (float)k * (1.0f/65536.0f), &sn, &cs);
    cplx r  = cmk(cs, sn);
    cplx r2 = cmul(r, r);
    cplx r4 = cmul(r2, r2);
    cplx r8 = cmul(r4, r4);
    cplx av[8];
    #pragma unroll
    for (int v = 0; v < 8; ++v) av[v] = cmk(0.f, 0.f);
    cplx C = cmk(1.f, 0.f);
    #pragma unroll
    for (int u = 0; u < 16; ++u) {
      #pragma unroll
      for (int v = 0; v < 8; ++v) {
        float w = wt[fcL][u*8 + v];
        av[v].x += w * C.x;
        av[v].y += w * C.y;
      }
      C = cmul(C, r8);
    }
    cplx acc = av[7];
    #pragma unroll
    for (int v = 6; v >= 0; --v) acc = cadd(av[v], cmul(r, acc));
    Y2[((long)k1*129 + m)*128 + fc] = acc;
  }
}

// Fused middle stage, NL=2: each block processes TWO n-values for its
// column pair, so every Y2 line loaded feeds two MACs (halves Y2 traffic,
// doubles per-load arithmetic — the round-1 version was load-latency-bound
// at VALUBusy 29%).
__global__ __launch_bounds__(256, 2)
void fused_mid(const cplx* __restrict__ T1, const cplx* __restrict__ Y2,
               cplx* __restrict__ T2, int Bn) {
  const int lnp = blockIdx.x;          // local n PAIR within batch
  const int p   = blockIdx.y;          // pair entry 0..128
  const int cLo = p;
  const int cHi = (256 - p) & 255;
  const bool selfp = (p == 0) || (p == 128);
  const int t = threadIdx.x;
  const int g = t >> 4;                // 16 groups of 16 lanes (wave-aligned)
  const int j = t & 15;
  const int c = g & 7;
  const int half = g >> 3;
  const int col = half ? cHi : cLo;

  __shared__ cplx Ts[16][260];         // per-group transpose / Z-exchange rows
  __shared__ cplx Xs[2][8][2][130];    // unpacked X[sub][c][half][m]

  const float C16 = 0.98078528040323044913f;  // cos(pi/16)
  const float S16 = 0.19509032201612826785f;  // sin(pi/16)

  // ---- Phase F twice: forward DFT-256 over b + real-FFT unpack ----
  #pragma unroll
  for (int sub = 0; sub < 2; ++sub) {
    const int ln = lnp*2 + sub;
    const bool v = (ln < Bn);
    cplx x[16];
    if (v) {
      const cplx* src = T1 + ((long)(ln*8 + c) * NFFT + (long)col * 256);
      #pragma unroll
      for (int a1 = 0; a1 < 16; ++a1) x[a1] = src[a1*16 + j];
      dft16<-1>(x);
      {
        float sn, cs;
        __sincosf(-6.28318530717958648f * (float)j * (1.0f/256.0f), &sn, &cs);
        cplx r = cmk(cs, sn), cur = r;
        #pragma unroll
        for (int t1 = 1; t1 < 16; ++t1) { x[t1] = cmul(x[t1], cur); cur = cmul(cur, r); }
      }
      #pragma unroll
      for (int t1 = 0; t1 < 16; ++t1) Ts[g][t1*16 + ((j + t1) & 15)] = x[t1];
      #pragma unroll
      for (int a2 = 0; a2 < 16; ++a2) x[a2] = Ts[g][j*16 + ((a2 + j) & 15)];
      dft16<-1>(x);
      #pragma unroll
      for (int t2 = 0; t2 < 16; ++t2) Ts[g][j + 16*t2] = x[t2];
    }
    __syncthreads();
    if (v) {
      float sn, cs;
      __sincosf(-3.14159265358979324f * (float)(col + 256*j) * (1.0f/65536.0f), &sn, &cs);
      cplx w = cmk(cs, sn);
      const cplx stp = cmk(C16, -S16);
      #pragma unroll
      for (int t2 = 0; t2 < 8; ++t2) {
        int m = j + 16*t2;
        int k = col + 256*m;
        cplx zk = x[t2];
        int mi = (65536 - k) & 65535;
        cplx zm = Ts[g ^ 8][mi >> 8];
        cplx E = cmk(0.5f*(zk.x + zm.x), 0.5f*(zk.y - zm.y));
        cplx D = cmk(zk.x - zm.x, zk.y + zm.y);
        cplx O = cmk(0.5f*D.y, -0.5f*D.x);
        Xs[sub][c][half][m] = cadd(E, cmul(w, O));
        w = cmul(w, stp);
      }
      if (p == 0 && half == 0 && j == 0) {
        cplx zk = x[8];
        cplx X = cmk(zk.x, -zk.y);
        Xs[sub][c][0][128] = X;
        Xs[sub][c][1][128] = X;
      }
    }
    __syncthreads();                   // Ts free for next sub / M transposes
  }

  // ---- Phase M: shared-Y2 MAC for both subs + Hermitian pack + inverse ----
  const int f = g;
  const int ln0 = lnp*2;
  const bool v1 = (ln0 + 1 < Bn);
  #pragma unroll 1
  for (int r = 0; r < 2; ++r) {
    if (r == 1 && selfp) break;
    const int mcol = r ? cHi : cLo;
    const int colP = (256 - mcol) & 255;
    cplx z0[16], z1[16];
    // direct half: m = 0..127, bin k = mcol + 256m
    {
      float sn, cs;
      __sincosf(3.14159265358979324f * (float)(mcol + 256*j) * (1.0f/65536.0f), &sn, &cs);
      cplx wp = cmk(cs, sn);
      const cplx stp = cmk(C16, S16);
      #pragma unroll
      for (int t2 = 0; t2 < 8; ++t2) {
        int m = j + 16*t2;
        const float4* yv = reinterpret_cast<const float4*>(
            Y2 + (((long)mcol*129 + m)*128 + f*8));
        float4 y0 = yv[0], y1 = yv[1], y2 = yv[2], y3 = yv[3];
        cplx S0 = cmulj(Xs[0][0][r][m], cmk(y0.x, y0.y));
        S0 = cadd(S0, cmulj(Xs[0][1][r][m], cmk(y0.z, y0.w)));
        S0 = cadd(S0, cmulj(Xs[0][2][r][m], cmk(y1.x, y1.y)));
        S0 = cadd(S0, cmulj(Xs[0][3][r][m], cmk(y1.z, y1.w)));
        S0 = cadd(S0, cmulj(Xs[0][4][r][m], cmk(y2.x, y2.y)));
        S0 = cadd(S0, cmulj(Xs[0][5][r][m], cmk(y2.z, y2.w)));
        S0 = cadd(S0, cmulj(Xs[0][6][r][m], cmk(y3.x, y3.y)));
        S0 = cadd(S0, cmulj(Xs[0][7][r][m], cmk(y3.z, y3.w)));
        cplx E2 = cmk(0.5f*S0.x, 0.5f*S0.y);
        cplx O2 = cmul(wp, E2);
        z0[t2] = cmk(E2.x - O2.y, E2.y + O2.x);
        if (v1) {
          cplx S1 = cmulj(Xs[1][0][r][m], cmk(y0.x, y0.y));
          S1 = cadd(S1, cmulj(Xs[1][1][r][m], cmk(y0.z, y0.w)));
          S1 = cadd(S1, cmulj(Xs[1][2][r][m], cmk(y1.x, y1.y)));
          S1 = cadd(S1, cmulj(Xs[1][3][r][m], cmk(y1.z, y1.w)));
          S1 = cadd(S1, cmulj(Xs[1][4][r][m], cmk(y2.x, y2.y)));
          S1 = cadd(S1, cmulj(Xs[1][5][r][m], cmk(y2.z, y2.w)));
          S1 = cadd(S1, cmulj(Xs[1][6][r][m], cmk(y3.x, y3.y)));
          S1 = cadd(S1, cmulj(Xs[1][7][r][m], cmk(y3.z, y3.w)));
          cplx E3 = cmk(0.5f*S1.x, 0.5f*S1.y);
          cplx O3 = cmul(wp, E3);
          z1[t2] = cmk(E3.x - O3.y, E3.y + O3.x);
        }
        wp = cmul(wp, stp);
      }
    }
    // mirror half: m = 128..255, bin kp = 65536 - mcol - 256m (column colP)
    {
      int kp0 = 32768 - mcol - 256*j;
      float sn, cs;
      __sincosf(3.14159265358979324f * (float)kp0 * (1.0f/65536.0f), &sn, &cs);
      cplx wq = cmk(cs, sn);
      const cplx stp = cmk(C16, -S16);
      #pragma unroll
      for (int t2 = 8; t2 < 16; ++t2) {
        int kp = kp0 - 4096*(t2 - 8);
        int mm = kp >> 8;
        const float4* yv = reinterpret_cast<const float4*>(
            Y2 + (((long)colP*129 + mm)*128 + f*8));
        float4 y0 = yv[0], y1 = yv[1], y2 = yv[2], y3 = yv[3];
        cplx S0 = cmulj(Xs[0][0][1-r][mm], cmk(y0.x, y0.y));
        S0 = cadd(S0, cmulj(Xs[0][1][1-r][mm], cmk(y0.z, y0.w)));
        S0 = cadd(S0, cmulj(Xs[0][2][1-r][mm], cmk(y1.x, y1.y)));
        S0 = cadd(S0, cmulj(Xs[0][3][1-r][mm], cmk(y1.z, y1.w)));
        S0 = cadd(S0, cmulj(Xs[0][4][1-r][mm], cmk(y2.x, y2.y)));
        S0 = cadd(S0, cmulj(Xs[0][5][1-r][mm], cmk(y2.z, y2.w)));
        S0 = cadd(S0, cmulj(Xs[0][6][1-r][mm], cmk(y3.x, y3.y)));
        S0 = cadd(S0, cmulj(Xs[0][7][1-r][mm], cmk(y3.z, y3.w)));
        cplx E2 = cmk(0.5f*S0.x, 0.5f*S0.y);
        cplx O2 = cmul(wq, E2);
        z0[t2] = cmk(E2.x + O2.y, O2.x - E2.y);
        if (v1) {
          cplx S1 = cmulj(Xs[1][0][1-r][mm], cmk(y0.x, y0.y));
          S1 = cadd(S1, cmulj(Xs[1][1][1-r][mm], cmk(y0.z, y0.w)));
          S1 = cadd(S1, cmulj(Xs[1][2][1-r][mm], cmk(y1.x, y1.y)));
          S1 = cadd(S1, cmulj(Xs[1][3][1-r][mm], cmk(y1.z, y1.w)));
          S1 = cadd(S1, cmulj(Xs[1][4][1-r][mm], cmk(y2.x, y2.y)));
          S1 = cadd(S1, cmulj(Xs[1][5][1-r][mm], cmk(y2.z, y2.w)));
          S1 = cadd(S1, cmulj(Xs[1][6][1-r][mm], cmk(y3.x, y3.y)));
          S1 = cadd(S1, cmulj(Xs[1][7][1-r][mm], cmk(y3.z, y3.w)));
          cplx E3 = cmk(0.5f*S1.x, 0.5f*S1.y);
          cplx O3 = cmul(wq, E3);
          z1[t2] = cmk(E3.x + O3.y, O3.x - E3.y);
        }
        wq = cmul(wq, stp);
      }
    }
    // inverse inner DFT-256 over k2 + big twiddle + store, per sub
    {
      dft16<1>(z0);
      {
        float sn, cs;
        __sincosf(6.28318530717958648f * (float)j * (1.0f/256.0f), &sn, &cs);
        cplx rr = cmk(cs, sn), cur = rr;
        #pragma unroll
        for (int t1 = 1; t1 < 16; ++t1) { z0[t1] = cmul(z0[t1], cur); cur = cmul(cur, rr); }
      }
      #pragma unroll
      for (int t1 = 0; t1 < 16; ++t1) Ts[g][t1*16 + ((j + t1) & 15)] = z0[t1];
      #pragma unroll
      for (int a2 = 0; a2 < 16; ++a2) z0[a2] = Ts[g][j*16 + ((a2 + j) & 15)];
      dft16<1>(z0);
      {
        float sn, cs;
        __sincosf(6.28318530717958648f * (float)(mcol*j) * (1.0f/65536.0f), &sn, &cs);
        cplx cur = cmk(cs, sn);
        __sincosf(6.28318530717958648f * (float)mcol * (1.0f/4096.0f), &sn, &cs);
        cplx stp2 = cmk(cs, sn);
        cplx* dst = T2 + (long)(ln0*16 + f) * NFFT + (long)mcol * 256;
        #pragma unroll
        for (int t2 = 0; t2 < 16; ++t2) {
          dst[j + 16*t2] = cmul(z0[t2], cur);
          cur = cmul(cur, stp2);
        }
      }
    }
    if (v1) {
      dft16<1>(z1);
      {
        float sn, cs;
        __sincosf(6.28318530717958648f * (float)j * (1.0f/256.0f), &sn, &cs);
        cplx rr = cmk(cs, sn), cur = rr;
        #pragma unroll
        for (int t1 = 1; t1 < 16; ++t1) { z1[t1] = cmul(z1[t1], cur); cur = cmul(cur, rr); }
      }
      #pragma unroll
      for (int t1 = 0; t1 < 16; ++t1) Ts[g][t1*16 + ((j + t1) & 15)] = z1[t1];
      #pragma unroll
      for (int a2 = 0; a2 < 16; ++a2) z1[a2] = Ts[g][j*16 + ((a2 + j) & 15)];
      dft16<1>(z1);
      {
        float sn, cs;
        __sincosf(6.28318530717958648f * (float)(mcol*j) * (1.0f/65536.0f), &sn, &cs);
        cplx cur = cmk(cs, sn);
        __sincosf(6.28318530717958648f * (float)mcol * (1.0f/4096.0f), &sn, &cs);
        cplx stp2 = cmk(cs, sn);
        cplx* dst = T2 + (long)((ln0+1)*16 + f) * NFFT + (long)mcol * 256;
        #pragma unroll
        for (int t2 = 0; t2 < 16; ++t2) {
          dst[j + 16*t2] = cmul(z1[t2], cur);
          cur = cmul(cur, stp2);
        }
      }
    }
  }
}

} // namespace

extern "C" void kernel_launch(void* const* d_in, const int* in_sizes, int n_in,
                              void* d_out, int out_size, void* d_ws, size_t ws_size,
                              hipStream_t stream) {
  const cplx*  x    = (const cplx*)d_in[0];   // (32,8,65536) f32 = 32768 cplx/seq
  const float* wgt  = (const float*)d_in[1];  // (16,8,128)
  const float* bias = (const float*)d_in[2];  // (16,)
  float* out = (float*)d_out;                 // (32,16,65409)

  // Workspace: Y2 (33.8 MB) + T1 (Bn*4 MB) + T2 (Bn*8 MB).
  // Bn=16 -> fused_mid grid (8,129)=1032 blocks @ 2/CU = 2.02 scheduling
  // rounds (good backfill); smaller Bn gives pathological 512+epsilon tails.
  static const int BnOpt[5] = {16, 8, 4, 2, 1};
  int Bn = 1;
  for (int i = 0; i < 5; ++i) {
    size_t need = Y2BYTES + (size_t)BnOpt[i] * 12582912ull;
    if (need <= ws_size) { Bn = BnOpt[i]; break; }
  }
  char* ws = (char*)d_ws;
  cplx* Y2 = (cplx*)ws;
  cplx* T1 = (cplx*)(ws + Y2BYTES);
  cplx* T2 = (cplx*)(ws + Y2BYTES + (size_t)Bn * 4194304ull);

  weight_spec<<<dim3(256, 8), dim3(256), 0, stream>>>(wgt, Y2);

  for (int n0 = 0; n0 < 32; n0 += Bn) {
    fft_pass_a<-1><<<dim3(Bn*8*16), dim3(256), 0, stream>>>(
        x + (long)n0*8*32768, 32768, 32768, T1);
    fused_mid<<<dim3((Bn + 1)/2, 129), dim3(256), 0, stream>>>(T1, Y2, T2, Bn);
    fft_pass_b<1,1><<<dim3(Bn*16*16), dim3(256), 0, stream>>>(
        T2, (cplx*)nullptr, out, bias, n0*16);
  }
}

// Round 3
// 639.262 us; speedup vs baseline: 2.4887x; 2.4887x over previous
//
#include <hip/hip_runtime.h>

namespace {

constexpr int NFFT  = 65536;   // complex FFT length (half of 131072)
constexpr int OUTW  = 65409;   // W - K + 1
// Y2[k1][m][f][c] : weight rfft spectrum, column-major for the fused MAC
constexpr size_t Y2BYTES = (size_t)256 * 129 * 128 * 8;

typedef float2 cplx;

__device__ __forceinline__ cplx cmk(float x, float y){ return make_float2(x, y); }
__device__ __forceinline__ cplx cadd(cplx a, cplx b){ return cmk(a.x+b.x, a.y+b.y); }
__device__ __forceinline__ cplx csub(cplx a, cplx b){ return cmk(a.x-b.x, a.y-b.y); }
__device__ __forceinline__ cplx cmul(cplx a, cplx b){ return cmk(a.x*b.x - a.y*b.y, a.x*b.y + a.y*b.x); }
__device__ __forceinline__ cplx cmulj(cplx a, cplx b){ // a * conj(b)
  return cmk(a.x*b.x + a.y*b.y, a.y*b.x - a.x*b.y); }

// 16-point complex DFT, natural order in/out. DIR=-1 forward, +1 inverse (unnormalized).
template<int DIR>
__device__ __forceinline__ void dft16(cplx v[16]) {
  const float C1 = 0.92387953251128674f;
  const float S1 = 0.38268343236508977f;
  const float C2 = 0.70710678118654752f;
  const float WR[16]  = {1.f, C1, C2, S1, 0.f, -S1, -C2, -C1, -1.f, -C1, -C2, -S1, 0.f, S1, C2, C1};
  const float WIF[16] = {0.f, -S1, -C2, -C1, -1.f, -C1, -C2, -S1, 0.f, S1, C2, C1, 1.f, C1, C2, S1};
  cplx s[16];
  #pragma unroll
  for (int n2 = 0; n2 < 4; ++n2) {
    cplx a = v[n2], b = v[n2+4], c = v[n2+8], d = v[n2+12];
    cplx ac = cadd(a,c), am = csub(a,c), bd = cadd(b,d), bm = csub(b,d);
    cplx x0 = cadd(ac, bd), x2 = csub(ac, bd), x1, x3;
    if (DIR == -1) { x1 = cmk(am.x + bm.y, am.y - bm.x); x3 = cmk(am.x - bm.y, am.y + bm.x); }
    else           { x1 = cmk(am.x - bm.y, am.y + bm.x); x3 = cmk(am.x + bm.y, am.y - bm.x); }
    s[0*4+n2] = x0;
    {
      int e1 = (n2*1) & 15, e2 = (n2*2) & 15, e3 = (n2*3) & 15;
      cplx w1 = cmk(WR[e1], (DIR==-1)? WIF[e1] : -WIF[e1]);
      cplx w2 = cmk(WR[e2], (DIR==-1)? WIF[e2] : -WIF[e2]);
      cplx w3 = cmk(WR[e3], (DIR==-1)? WIF[e3] : -WIF[e3]);
      s[1*4+n2] = cmul(x1, w1);
      s[2*4+n2] = cmul(x2, w2);
      s[3*4+n2] = cmul(x3, w3);
    }
  }
  #pragma unroll
  for (int t1 = 0; t1 < 4; ++t1) {
    cplx a = s[t1*4+0], b = s[t1*4+1], c = s[t1*4+2], d = s[t1*4+3];
    cplx ac = cadd(a,c), am = csub(a,c), bd = cadd(b,d), bm = csub(b,d);
    cplx x0 = cadd(ac,bd), x2 = csub(ac,bd), x1, x3;
    if (DIR == -1) { x1 = cmk(am.x + bm.y, am.y - bm.x); x3 = cmk(am.x - bm.y, am.y + bm.x); }
    else           { x1 = cmk(am.x - bm.y, am.y + bm.x); x3 = cmk(am.x + bm.y, am.y - bm.x); }
    v[t1+0] = x0; v[t1+4] = x1; v[t1+8] = x2; v[t1+12] = x3;
  }
}

// Four-step pass A (forward): inner 256-pt DFTs + big twiddle.
// k1-major output staged through padded LDS so global stores are contiguous.
template<int DIR>
__global__ __launch_bounds__(256)
void fft_pass_a(const cplx* __restrict__ in, long inStride, int inLen,
                cplx* __restrict__ T) {
  int blk = blockIdx.x;
  int seq = blk >> 4;
  int B0  = (blk & 15) << 4;
  int t = threadIdx.x;
  __shared__ cplx sm[4608];                    // 36864 B: union of two views
  cplx (*tile)[260] = (cplx(*)[260])sm;        // phase-1 view [16][260]
  cplx* tile2 = sm;                            // phase-2 view [256][18]
  {
    const cplx* src = in + (long)seq * inStride;
    int cb = t & 15, rg = t >> 4;
    #pragma unroll
    for (int i = 0; i < 16; ++i) {
      int a = i*16 + rg;
      int sIdx = a*256 + B0 + cb;
      cplx v = (sIdx < inLen) ? src[sIdx] : cmk(0.f, 0.f);
      tile[cb][a] = v;
    }
  }
  __syncthreads();
  int cc = t >> 4, j = t & 15;
  cplx x[16];
  #pragma unroll
  for (int a1 = 0; a1 < 16; ++a1) x[a1] = tile[cc][a1*16 + j];
  dft16<DIR>(x);
  {
    float sn, cs;
    __sincosf((float)DIR * 6.28318530717958648f * (float)j * (1.0f/256.0f), &sn, &cs);
    cplx r = cmk(cs, sn), cur = r;
    #pragma unroll
    for (int t1 = 1; t1 < 16; ++t1) { x[t1] = cmul(x[t1], cur); cur = cmul(cur, r); }
  }
  __syncthreads();
  #pragma unroll
  for (int t1 = 0; t1 < 16; ++t1) tile[cc][t1*16 + ((j + t1) & 15)] = x[t1];
  __syncthreads();
  #pragma unroll
  for (int a2 = 0; a2 < 16; ++a2) x[a2] = tile[cc][j*16 + ((a2 + j) & 15)];
  dft16<DIR>(x);
  int b = B0 + cc;
  __syncthreads();   // tile reads done; reuse as tile2
  {
    float sn, cs;
    __sincosf((float)DIR * 6.28318530717958648f * (float)(b*j) * (1.0f/65536.0f), &sn, &cs);
    cplx cur = cmk(cs, sn);
    __sincosf((float)DIR * 6.28318530717958648f * (float)b * (1.0f/4096.0f), &sn, &cs);
    cplx stp = cmk(cs, sn);
    #pragma unroll
    for (int t2 = 0; t2 < 16; ++t2) {
      tile2[(j + 16*t2)*18 + cc] = cmul(x[t2], cur);
      cur = cmul(cur, stp);
    }
  }
  __syncthreads();
  {
    int rg = t >> 4, cb = t & 15;
    cplx* dst = T + (long)seq * NFFT + B0 + cb;
    #pragma unroll
    for (int i = 0; i < 16; ++i) {
      int k1 = i*16 + rg;
      dst[(long)k1 * 256] = tile2[k1*18 + cb];
    }
  }
}

// Four-step pass B: outer 256-pt DFTs. MODE 1 = inverse-final with bias+trunc.
template<int DIR, int MODE>
__global__ __launch_bounds__(256)
void fft_pass_b(const cplx* __restrict__ T, cplx* __restrict__ outZ,
                float* __restrict__ outR, const float* __restrict__ bias,
                int seqBase) {
  int blk = blockIdx.x;
  int seq = blk >> 4;
  int K0  = (blk & 15) << 4;
  int t = threadIdx.x;
  __shared__ cplx tile[16][260];
  {
    const cplx* src = T + (long)seq * NFFT;
    int ck = t & 15, rg = t >> 4;
    #pragma unroll
    for (int i = 0; i < 16; ++i) {
      int b = i*16 + rg;
      tile[ck][b] = src[b*256 + K0 + ck];
    }
  }
  __syncthreads();
  int cc = t >> 4, j = t & 15;
  cplx x[16];
  #pragma unroll
  for (int a1 = 0; a1 < 16; ++a1) x[a1] = tile[cc][a1*16 + j];
  dft16<DIR>(x);
  {
    float sn, cs;
    __sincosf((float)DIR * 6.28318530717958648f * (float)j * (1.0f/256.0f), &sn, &cs);
    cplx r = cmk(cs, sn), cur = r;
    #pragma unroll
    for (int t1 = 1; t1 < 16; ++t1) { x[t1] = cmul(x[t1], cur); cur = cmul(cur, r); }
  }
  __syncthreads();
  #pragma unroll
  for (int t1 = 0; t1 < 16; ++t1) tile[cc][t1*16 + ((j + t1) & 15)] = x[t1];
  __syncthreads();
  #pragma unroll
  for (int a2 = 0; a2 < 16; ++a2) x[a2] = tile[cc][j*16 + ((a2 + j) & 15)];
  dft16<DIR>(x);
  __syncthreads();
  #pragma unroll
  for (int t2 = 0; t2 < 16; ++t2) tile[cc][j + 16*t2] = x[t2];
  __syncthreads();
  int ck2 = t & 15, rg2 = t >> 4;
  if (MODE == 0) {
    cplx* dst = outZ + (long)seq * NFFT + K0 + ck2;
    #pragma unroll
    for (int i = 0; i < 16; ++i) {
      int k2 = i*16 + rg2;
      dst[256*k2] = tile[ck2][k2];
    }
  } else {
    const float sc = 1.0f / 65536.0f;
    int gseq = seqBase + seq;
    float bf = bias[gseq & 15];
    float* dst = outR + (long)gseq * OUTW;
    #pragma unroll
    for (int i = 0; i < 16; ++i) {
      int k2 = i*16 + rg2;
      int s  = K0 + ck2 + 256*k2;
      int tp = 2*s;
      cplx v = tile[ck2][k2];
      if (tp < OUTW)     dst[tp]   = v.x * sc + bf;
      if (tp + 1 < OUTW) dst[tp+1] = v.y * sc + bf;
    }
  }
}

// Direct weight rfft into transposed layout Y2[k1][m][f][c], k = k1 + 256*m.
__global__ __launch_bounds__(256)
void weight_spec(const float* __restrict__ wgt, cplx* __restrict__ Y2) {
  const int k1 = blockIdx.x;      // 0..255
  const int fg = blockIdx.y;      // 0..7
  const int t  = threadIdx.x;
  __shared__ float wt[16][129];
  for (int e = t; e < 16*128; e += 256)
    wt[e >> 7][e & 127] = wgt[(fg*16 + (e >> 7))*128 + (e & 127)];
  __syncthreads();
  const int fcL = t & 15;
  const int fc  = fg*16 + fcL;
  for (int m = t >> 4; m < 129; m += 16) {
    int k = k1 + 256*m;
    if (k > 32768) break;
    float sn, cs;
    __sincosf(-3.14159265358979324f * (float)k * (1.0f/65536.0f), &sn, &cs);
    cplx r  = cmk(cs, sn);
    cplx r2 = cmul(r, r);
    cplx r4 = cmul(r2, r2);
    cplx r8 = cmul(r4, r4);
    cplx av[8];
    #pragma unroll
    for (int v = 0; v < 8; ++v) av[v] = cmk(0.f, 0.f);
    cplx C = cmk(1.f, 0.f);
    #pragma unroll
    for (int u = 0; u < 16; ++u) {
      #pragma unroll
      for (int v = 0; v < 8; ++v) {
        float w = wt[fcL][u*8 + v];
        av[v].x += w * C.x;
        av[v].y += w * C.y;
      }
      C = cmul(C, r8);
    }
    cplx acc = av[7];
    #pragma unroll
    for (int v = 6; v >= 0; --v) acc = cadd(av[v], cmul(r, acc));
    Y2[((long)k1*129 + m)*128 + fc] = acc;
  }
}

// Fused middle stage v3. Key identity: bin K = 256m+q feeds BOTH
// Zfull[K] (col q, pos m) and Zfull[65536-K] (col 256-q, pos 255-m) with the
// SAME product S(K) and SAME twiddle e^{i pi K/65536} — only the packing
// differs. So each pass over column q computes each S once, packs twice,
// and ships the mirror value to lane j^15 via shfl. Halves both MAC FLOPs
// and Y2 loads vs the round-1 two-round structure. No VGPR cap (round-2's
// launch_bounds(256,2) caused the 1-GB spill traffic).
__global__ __launch_bounds__(256)
void fused_mid(const cplx* __restrict__ T1, const cplx* __restrict__ Y2,
               cplx* __restrict__ T2) {
  const int ln  = blockIdx.x;
  const int p   = blockIdx.y;          // 0..128
  const int cLo = p;
  const int cHi = (256 - p) & 255;
  const bool selfp = (p == 0) || (p == 128);
  const int t = threadIdx.x;
  const int g = t >> 4;                // 16 groups of 16 lanes (wave-aligned)
  const int j = t & 15;
  const int c = g & 7;
  const int half = g >> 3;
  const int col = half ? cHi : cLo;

  __shared__ cplx Ts[16][260];
  __shared__ cplx Xs[8][2][130];

  const float C16 = 0.98078528040323044913f;  // cos(pi/16)
  const float S16 = 0.19509032201612826785f;  // sin(pi/16)

  // ---- Phase F: forward DFT-256 over b, one column per group-half ----
  cplx x[16];
  {
    const cplx* src = T1 + ((long)(ln*8 + c) * NFFT + (long)col * 256);
    #pragma unroll
    for (int a1 = 0; a1 < 16; ++a1) x[a1] = src[a1*16 + j];
  }
  dft16<-1>(x);
  {
    float sn, cs;
    __sincosf(-6.28318530717958648f * (float)j * (1.0f/256.0f), &sn, &cs);
    cplx r = cmk(cs, sn), cur = r;
    #pragma unroll
    for (int t1 = 1; t1 < 16; ++t1) { x[t1] = cmul(x[t1], cur); cur = cmul(cur, r); }
  }
  #pragma unroll
  for (int t1 = 0; t1 < 16; ++t1) Ts[g][t1*16 + ((j + t1) & 15)] = x[t1];
  #pragma unroll
  for (int a2 = 0; a2 < 16; ++a2) x[a2] = Ts[g][j*16 + ((a2 + j) & 15)];
  dft16<-1>(x);
  #pragma unroll
  for (int t2 = 0; t2 < 16; ++t2) Ts[g][j + 16*t2] = x[t2];
  __syncthreads();

  // ---- real-FFT unpack: X[k] = E + w*O for kept bins ----
  {
    float sn, cs;
    __sincosf(-3.14159265358979324f * (float)(col + 256*j) * (1.0f/65536.0f), &sn, &cs);
    cplx w = cmk(cs, sn);
    const cplx stp = cmk(C16, -S16);
    #pragma unroll
    for (int t2 = 0; t2 < 8; ++t2) {
      int m = j + 16*t2;
      int k = col + 256*m;
      cplx zk = x[t2];
      int mi = (65536 - k) & 65535;
      cplx zm = Ts[g ^ 8][mi >> 8];
      cplx E = cmk(0.5f*(zk.x + zm.x), 0.5f*(zk.y - zm.y));
      cplx D = cmk(zk.x - zm.x, zk.y + zm.y);
      cplx O = cmk(0.5f*D.y, -0.5f*D.x);
      Xs[c][half][m] = cadd(E, cmul(w, O));
      w = cmul(w, stp);
    }
  }
  if (p == 0 && half == 0 && j == 0) {
    cplx zk = x[8];
    cplx X = cmk(zk.x, -zk.y);
    Xs[c][0][128] = X;
    Xs[c][1][128] = X;
  }
  __syncthreads();

  // ---- Phase M: one MAC per bin, pack twice, shfl the mirror half ----
  const int f = g;
  cplx zA[16], zB[16];

#define MAC_PASS(Q, XSEL, ZD, ZM, SRCLANE)                                     \
  do {                                                                         \
    const int q_ = (Q);                                                        \
    float sn_, cs_;                                                            \
    __sincosf(3.14159265358979324f * (float)(q_ + 256*j) * (1.0f/65536.0f),    \
              &sn_, &cs_);                                                     \
    cplx wp = cmk(cs_, sn_);                                                   \
    const cplx stp = cmk(C16, S16);                                            \
    const float4* yb = reinterpret_cast<const float4*>(                        \
        Y2 + ((long)q_*129 + j)*128 + f*8);                                    \
    float4 b0 = yb[0], b1 = yb[1], b2 = yb[2], b3 = yb[3];                     \
    _Pragma("unroll")                                                          \
    for (int t2 = 0; t2 < 8; ++t2) {                                           \
      float4 y0 = b0, y1 = b1, y2 = b2, y3 = b3;                               \
      if (t2 < 7) {                                                            \
        const float4* nx = yb + (long)(t2+1)*1024;                             \
        b0 = nx[0]; b1 = nx[1]; b2 = nx[2]; b3 = nx[3];                        \
      }                                                                        \
      int m = j + 16*t2;                                                       \
      cplx S = cmulj(Xs[0][XSEL][m], cmk(y0.x, y0.y));                         \
      S = cadd(S, cmulj(Xs[1][XSEL][m], cmk(y0.z, y0.w)));                     \
      S = cadd(S, cmulj(Xs[2][XSEL][m], cmk(y1.x, y1.y)));                     \
      S = cadd(S, cmulj(Xs[3][XSEL][m], cmk(y1.z, y1.w)));                     \
      S = cadd(S, cmulj(Xs[4][XSEL][m], cmk(y2.x, y2.y)));                     \
      S = cadd(S, cmulj(Xs[5][XSEL][m], cmk(y2.z, y2.w)));                     \
      S = cadd(S, cmulj(Xs[6][XSEL][m], cmk(y3.x, y3.y)));                     \
      S = cadd(S, cmulj(Xs[7][XSEL][m], cmk(y3.z, y3.w)));                     \
      cplx E2 = cmk(0.5f*S.x, 0.5f*S.y);                                       \
      cplx O2 = cmul(wp, E2);                                                  \
      ZD[t2] = cmk(E2.x - O2.y, E2.y + O2.x);                                  \
      float mx = E2.x + O2.y;                                                  \
      float my = O2.x - E2.y;                                                  \
      mx = __shfl(mx, (SRCLANE));                                              \
      my = __shfl(my, (SRCLANE));                                              \
      ZM[15 - t2] = cmk(mx, my);                                               \
      wp = cmul(wp, stp);                                                      \
    }                                                                          \
  } while (0)

  if (p == 0) {
    // q=0: mirror map is pos 256-m (not 255-m) -> src lane (16-j)&15 and a
    // one-slot shift fixup on lane j==0, plus explicit k=32768 boundary bin.
    int src0 = (t & ~15) | ((16 - j) & 15);
    MAC_PASS(0, 0, zA, zA, src0);
    if (j == 0) {
      zA[15] = zA[14]; zA[14] = zA[13]; zA[13] = zA[12]; zA[12] = zA[11];
      zA[11] = zA[10]; zA[10] = zA[9];  zA[9]  = zA[8];
      const float4* yv = reinterpret_cast<const float4*>(Y2 + (long)128*128 + f*8);
      float4 y0 = yv[0], y1 = yv[1], y2 = yv[2], y3 = yv[3];
      cplx S = cmulj(Xs[0][1][128], cmk(y0.x, y0.y));
      S = cadd(S, cmulj(Xs[1][1][128], cmk(y0.z, y0.w)));
      S = cadd(S, cmulj(Xs[2][1][128], cmk(y1.x, y1.y)));
      S = cadd(S, cmulj(Xs[3][1][128], cmk(y1.z, y1.w)));
      S = cadd(S, cmulj(Xs[4][1][128], cmk(y2.x, y2.y)));
      S = cadd(S, cmulj(Xs[5][1][128], cmk(y2.z, y2.w)));
      S = cadd(S, cmulj(Xs[6][1][128], cmk(y3.x, y3.y)));
      S = cadd(S, cmulj(Xs[7][1][128], cmk(y3.z, y3.w)));
      zA[8] = cmk(S.x, -S.y);
    }
  } else if (selfp) {            // p == 128
    MAC_PASS(128, 0, zA, zA, t ^ 15);
  } else {
    MAC_PASS(cLo, 0, zA, zB, t ^ 15);
    MAC_PASS(cHi, 1, zB, zA, t ^ 15);
  }
#undef MAC_PASS

  // ---- inverse inner DFT-256 over k2 + big twiddle + store ----
#define INV_STORE(Z, MCOL)                                                     \
  do {                                                                         \
    dft16<1>(Z);                                                               \
    {                                                                          \
      float sn_, cs_;                                                          \
      __sincosf(6.28318530717958648f * (float)j * (1.0f/256.0f), &sn_, &cs_);  \
      cplx rr = cmk(cs_, sn_), cur = rr;                                       \
      _Pragma("unroll")                                                        \
      for (int t1 = 1; t1 < 16; ++t1) { Z[t1] = cmul(Z[t1], cur); cur = cmul(cur, rr); } \
    }                                                                          \
    _Pragma("unroll")                                                          \
    for (int t1 = 0; t1 < 16; ++t1) Ts[g][t1*16 + ((j + t1) & 15)] = Z[t1];    \
    _Pragma("unroll")                                                          \
    for (int a2 = 0; a2 < 16; ++a2) Z[a2] = Ts[g][j*16 + ((a2 + j) & 15)];     \
    dft16<1>(Z);                                                               \
    {                                                                          \
      float sn_, cs_;                                                          \
      __sincosf(6.28318530717958648f * (float)((MCOL)*j) * (1.0f/65536.0f), &sn_, &cs_); \
      cplx cur = cmk(cs_, sn_);                                                \
      __sincosf(6.28318530717958648f * (float)(MCOL) * (1.0f/4096.0f), &sn_, &cs_); \
      cplx stp2 = cmk(cs_, sn_);                                               \
      cplx* dst = T2 + (long)(ln*16 + f) * NFFT + (long)(MCOL) * 256;          \
      _Pragma("unroll")                                                        \
      for (int t2 = 0; t2 < 16; ++t2) {                                        \
        dst[j + 16*t2] = cmul(Z[t2], cur);                                     \
        cur = cmul(cur, stp2);                                                 \
      }                                                                        \
    }                                                                          \
  } while (0)

  INV_STORE(zA, cLo);
  if (!selfp) INV_STORE(zB, cHi);
#undef INV_STORE
}

} // namespace

extern "C" void kernel_launch(void* const* d_in, const int* in_sizes, int n_in,
                              void* d_out, int out_size, void* d_ws, size_t ws_size,
                              hipStream_t stream) {
  const cplx*  x    = (const cplx*)d_in[0];   // (32,8,65536) f32 = 32768 cplx/seq
  const float* wgt  = (const float*)d_in[1];  // (16,8,128)
  const float* bias = (const float*)d_in[2];  // (16,)
  float* out = (float*)d_out;                 // (32,16,65409)

  // Workspace: Y2 (33.8 MB) + T1 (Bn*4 MB) + T2 (Bn*8 MB).
  static const int BnOpt[5] = {16, 8, 4, 2, 1};
  int Bn = 1;
  for (int i = 0; i < 5; ++i) {
    size_t need = Y2BYTES + (size_t)BnOpt[i] * 12582912ull;
    if (need <= ws_size) { Bn = BnOpt[i]; break; }
  }
  char* ws = (char*)d_ws;
  cplx* Y2 = (cplx*)ws;
  cplx* T1 = (cplx*)(ws + Y2BYTES);
  cplx* T2 = (cplx*)(ws + Y2BYTES + (size_t)Bn * 4194304ull);

  weight_spec<<<dim3(256, 8), dim3(256), 0, stream>>>(wgt, Y2);

  for (int n0 = 0; n0 < 32; n0 += Bn) {
    fft_pass_a<-1><<<dim3(Bn*8*16), dim3(256), 0, stream>>>(
        x + (long)n0*8*32768, 32768, 32768, T1);
    fused_mid<<<dim3(Bn, 129), dim3(256), 0, stream>>>(T1, Y2, T2);
    fft_pass_b<1,1><<<dim3(Bn*16*16), dim3(256), 0, stream>>>(
        T2, (cplx*)nullptr, out, bias, n0*16);
  }
}